// Round 7
// baseline (261.684 us; speedup 1.0000x reference)
//
#include <hip/hip_runtime.h>

#define NPTS 4096
#define NBATCH 4
#define HDIM 192
#define CDIM 384

typedef _Float16 f16x8 __attribute__((ext_vector_type(8)));
typedef float f32x4 __attribute__((ext_vector_type(4)));

// ---------------- K0: W2 [192][384] f32 -> W2T [384][192] f16 ----------------
__global__ __launch_bounds__(256) void prep_w2(const float* __restrict__ W2,
                                               _Float16* __restrict__ W2T) {
  int i = blockIdx.x * 256 + threadIdx.x;
  if (i < HDIM * CDIM) {
    int h = i / CDIM, c = i % CDIM;
    W2T[c * HDIM + h] = (_Float16)W2[i];
  }
}

// ---------------- K1: KNN, filter-then-prune + per-query SHARED threshold ----------------
// (unchanged from R6 — shared threshold gave ~-20us)
#define SCAP 30
#define FINF 3.4e38f

// macro, not lambda: a [&] lambda address-takes dl/il -> scratch spill (R2 lesson)
#define PRUNE()                                                                      \
  do {                                                                               \
    int mc = cnt;                                                                    \
    _Pragma("unroll")                                                                \
    for (int s = 32; s; s >>= 1) { int o = __shfl_xor(mc, s); mc = mc > o ? mc : o; }\
    mc = __builtin_amdgcn_readfirstlane(mc);                                         \
    for (int e = 0; e < mc; ++e) {                                                   \
      const int j = sstk[sbase + e] & 4095;                                          \
      const float dx = qx - spx[j];                                                  \
      const float dy = qy - spy[j];                                                  \
      const float dz = qz - spz[j];                                                  \
      const float d = __fadd_rn(__fadd_rn(__fmul_rn(dx, dx), __fmul_rn(dy, dy)),     \
                                __fmul_rn(dz, dz));                                  \
      const float v = (e < cnt && d < dl[15]) ? d : FINF;                            \
      bool cc[16];                                                                   \
      _Pragma("unroll")                                                              \
      for (int i = 0; i < 16; ++i) cc[i] = v < dl[i];                                \
      _Pragma("unroll")                                                              \
      for (int i = 15; i >= 1; --i) {                                                \
        dl[i] = cc[i] ? (cc[i - 1] ? dl[i - 1] : v) : dl[i];                         \
        il[i] = cc[i] ? (cc[i - 1] ? il[i - 1] : j) : il[i];                         \
      }                                                                              \
      dl[0] = cc[0] ? v : dl[0];                                                     \
      il[0] = cc[0] ? j : il[0];                                                     \
    }                                                                                \
    cnt = 0;                                                                         \
    thr = dl[15];                                                                    \
    atomicMin(&sThrU[ql], __float_as_uint(dl[15]));                                  \
  } while (0)

__global__ __launch_bounds__(512) void knn_kernel(const float* __restrict__ pts,
                                                  int* __restrict__ idx_out) {
  __shared__ float smem[12352];
  __shared__ float sstk_f[7680];
  __shared__ unsigned sThrU[32];
  unsigned short* sstk = (unsigned short*)sstk_f;

  float* spx = smem;
  float* spy = smem + 4096;
  float* spz = smem + 8192;

  const int t  = threadIdx.x;
  const int b  = blockIdx.x >> 7;
  const int qb = (blockIdx.x & 127) << 5;
  const float* P = pts + (size_t)b * NPTS * 3;

  for (int i = t; i < NPTS; i += 512) {
    spx[i] = P[3 * i + 0];
    spy[i] = P[3 * i + 1];
    spz[i] = P[3 * i + 2];
  }
  if (t < 32) sThrU[t] = __float_as_uint(FINF);
  __syncthreads();

  const int ql    = t & 31;
  const int q     = qb + ql;
  const int cid   = (t >> 5) & 15;
  const int cbase = cid << 8;
  const float qx = spx[q], qy = spy[q], qz = spz[q];

  float dl[16];
  int   il[16];
#pragma unroll
  for (int i = 0; i < 16; ++i) { dl[i] = FINF; il[i] = 0; }
  float thr = FINF;
  int   cnt = 0;
  const int sbase = t * SCAP;

  for (int jt = 0; jt < 256; jt += 8) {
    {  // refresh admission threshold (volatile: must observe other waves' atomicMin)
      const unsigned tb = ((volatile unsigned*)sThrU)[ql];
      thr = fminf(dl[15], __uint_as_float(tb));
    }
    const int jb = cbase + jt;
    const f32x4 x0 = *(const f32x4*)(spx + jb);
    const f32x4 x1 = *(const f32x4*)(spx + jb + 4);
    const f32x4 y0 = *(const f32x4*)(spy + jb);
    const f32x4 y1 = *(const f32x4*)(spy + jb + 4);
    const f32x4 z0 = *(const f32x4*)(spz + jb);
    const f32x4 z1 = *(const f32x4*)(spz + jb + 4);
#pragma unroll
    for (int u = 0; u < 8; ++u) {
      const float px = (u < 4) ? x0[u & 3] : x1[u & 3];
      const float py = (u < 4) ? y0[u & 3] : y1[u & 3];
      const float pz = (u < 4) ? z0[u & 3] : z1[u & 3];
      const float dx = qx - px;
      const float dy = qy - py;
      const float dz = qz - pz;
      // EXACT match to numpy/jax: ((dx*dx + dy*dy) + dz*dz), f32, no FMA contraction
      const float d = __fadd_rn(__fadd_rn(__fmul_rn(dx, dx), __fmul_rn(dy, dy)),
                                __fmul_rn(dz, dz));
      if (d <= thr) { sstk[sbase + cnt] = (unsigned short)(jb + u); ++cnt; }
    }
    if (__any(cnt >= SCAP - 8)) PRUNE();
  }
  PRUNE();

  __syncthreads();

  float*          md = smem;
  unsigned short* mi = (unsigned short*)(smem + 8224);
  const int lbase = ql * 257 + cid * 16;
#pragma unroll
  for (int i = 0; i < 16; ++i) {
    md[lbase + i] = dl[i];
    mi[lbase + i] = (unsigned short)il[i];
  }
  __syncthreads();

  float*          od = sstk_f;
  unsigned short* oi = (unsigned short*)(sstk_f + 2080);
  if (t < 128) {
    const int mq = t >> 2, g = t & 3;
    const int base = mq * 257 + g * 64;
    int p0 = 0, p1 = 0, p2 = 0, p3 = 0;
    const int ob = mq * 65 + g * 16;
    for (int r = 0; r < 16; ++r) {
      const float d0 = md[base + p0];
      const float d1 = md[base + 16 + p1];
      const float d2 = md[base + 32 + p2];
      const float d3 = md[base + 48 + p3];
      int bw = 0; float bd = d0;
      if (d1 < bd) { bd = d1; bw = 1; }
      if (d2 < bd) { bd = d2; bw = 2; }
      if (d3 < bd) { bd = d3; bw = 3; }
      const unsigned short bi = (bw == 0) ? mi[base + p0]
                              : (bw == 1) ? mi[base + 16 + p1]
                              : (bw == 2) ? mi[base + 32 + p2]
                                          : mi[base + 48 + p3];
      od[ob + r] = bd;
      oi[ob + r] = bi;
      p0 += (bw == 0); p1 += (bw == 1); p2 += (bw == 2); p3 += (bw == 3);
    }
  }
  __syncthreads();

  if (t < 32) {
    const int base = t * 65;
    int p0 = 0, p1 = 0, p2 = 0, p3 = 0;
    int* op = idx_out + (((size_t)b * NPTS + qb + t) << 4);
    for (int r = 0; r < 16; ++r) {
      const float d0 = od[base + p0];
      const float d1 = od[base + 16 + p1];
      const float d2 = od[base + 32 + p2];
      const float d3 = od[base + 48 + p3];
      int bw = 0; float bd = d0;
      if (d1 < bd) { bd = d1; bw = 1; }
      if (d2 < bd) { bd = d2; bw = 2; }
      if (d3 < bd) { bd = d3; bw = 3; }
      const unsigned short bi = (bw == 0) ? oi[base + p0]
                              : (bw == 1) ? oi[base + 16 + p1]
                              : (bw == 2) ? oi[base + 32 + p2]
                                          : oi[base + 48 + p3];
      op[r] = (int)bi;
      p0 += (bw == 0); p1 += (bw == 1); p2 += (bw == 2); p3 += (bw == 3);
    }
  }
}

// ---------------- K2: fused layer1(swish) -> f16 MFMA layer2 -> maxpool ----------------
// Wave = (qi-pair, 12 ct-tiles). A-frags (6kt x 2qi = 48 VGPR) ds_read ONCE and PINNED
// via asm "+v" — R6 showed the compiler otherwise rematerializes the ds_reads inside
// the ct-loop (VGPR_Count collapsed to 48, A re-read 12x, 183us). Pin makes the loaded
// value opaque so it must stay resident.
__global__ __launch_bounds__(512) void mlp_kernel(const float* __restrict__ pts,
                                                  const int* __restrict__ idx,
                                                  const float* __restrict__ W1,
                                                  const float* __restrict__ b1,
                                                  const _Float16* __restrict__ W2T,
                                                  const float* __restrict__ b2,
                                                  float* __restrict__ out) {
  __shared__ _Float16 sA[24576];   // 48 KB, fragment-major, chunk position == lane

  const int bid = blockIdx.x;
  const int b   = bid >> 9;
  const int qb  = (bid & 511) << 3;
  const float* P = pts + (size_t)b * NPTS * 3;
  const int t = threadIdx.x;
  const int lane = t & 63;

  // ---- stage A = f16(swish(f @ W1 + b1)) ----
  {
    const int r  = t & 15;           // neighbor slot
    const int kg = (t >> 4) & 3;     // k-slice (lane == kg*16 + r)
    const int qi = t >> 6;           // query within block
    const int qq = qb + qi;
    const int nb = idx[(((size_t)b * NPTS + qq) << 4) + r];
    const float pqx = P[qq * 3 + 0], pqy = P[qq * 3 + 1], pqz = P[qq * 3 + 2];
    float f[6];
    f[0] = P[nb * 3 + 0] - pqx;
    f[1] = P[nb * 3 + 1] - pqy;
    f[2] = P[nb * 3 + 2] - pqz;
    f[3] = pqx; f[4] = pqy; f[5] = pqz;
#pragma unroll
    for (int kt = 0; kt < 6; ++kt) {
      const int h0 = kt * 32 + kg * 8;
      f32x4 a0 = *(const f32x4*)(b1 + h0);
      f32x4 a1 = *(const f32x4*)(b1 + h0 + 4);
#pragma unroll
      for (int in = 0; in < 6; ++in) {
        const f32x4 w0 = *(const f32x4*)(W1 + in * HDIM + h0);
        const f32x4 w1 = *(const f32x4*)(W1 + in * HDIM + h0 + 4);
        a0 += f[in] * w0;
        a1 += f[in] * w1;
      }
      f16x8 v;
#pragma unroll
      for (int j = 0; j < 4; ++j) {
        const float s0 = a0[j] * __builtin_amdgcn_rcpf(1.0f + __expf(-a0[j]));
        const float s1 = a1[j] * __builtin_amdgcn_rcpf(1.0f + __expf(-a1[j]));
        v[j]     = (_Float16)s0;
        v[j + 4] = (_Float16)s1;
      }
      *(f16x8*)(sA + (((kt * 8 + qi) * 64) + lane) * 8) = v;   // base + lane*16 B
    }
  }
  __syncthreads();

  // ---- MFMA phase: wave wv -> qi-pair (wv&3), ct-range [(wv>>2)*12, +12) ----
  const int wv   = t >> 6;
  const int ln15 = lane & 15;
  const int qi0  = (wv & 3) * 2;
  const int ct0  = (wv >> 2) * 12;

  f16x8 af0_0, af0_1, af1_0, af1_1, af2_0, af2_1;   // named: static indexing only
  f16x8 af3_0, af3_1, af4_0, af4_1, af5_0, af5_1;
#define LOAD_AF(kt, q2, dst)                                                       \
  dst = *(const f16x8*)(sA + (((kt * 8 + qi0 + q2) * 64) + lane) * 8);             \
  asm volatile("" : "+v"(dst));   /* pin: forbid remat of the ds_read */
  LOAD_AF(0, 0, af0_0) LOAD_AF(0, 1, af0_1)
  LOAD_AF(1, 0, af1_0) LOAD_AF(1, 1, af1_1)
  LOAD_AF(2, 0, af2_0) LOAD_AF(2, 1, af2_1)
  LOAD_AF(3, 0, af3_0) LOAD_AF(3, 1, af3_1)
  LOAD_AF(4, 0, af4_0) LOAD_AF(4, 1, af4_1)
  LOAD_AF(5, 0, af5_0) LOAD_AF(5, 1, af5_1)
#undef LOAD_AF

  const int kofs = (lane >> 4) * 8;
  float* op0 = out + ((size_t)b * NPTS + qb + qi0 + 0) * CDIM;
  float* op1 = out + ((size_t)b * NPTS + qb + qi0 + 1) * CDIM;

#pragma unroll 2
  for (int cc = 0; cc < 12; ++cc) {
    const int c = (ct0 + cc) * 16 + ln15;
    const _Float16* bp = W2T + (size_t)c * HDIM + kofs;
    f16x8 bfr[6];
#pragma unroll
    for (int kt = 0; kt < 6; ++kt) bfr[kt] = *(const f16x8*)(bp + kt * 32);

    f32x4 acc0 = {0.f, 0.f, 0.f, 0.f};
    f32x4 acc1 = {0.f, 0.f, 0.f, 0.f};
    acc0 = __builtin_amdgcn_mfma_f32_16x16x32_f16(af0_0, bfr[0], acc0, 0, 0, 0);
    acc1 = __builtin_amdgcn_mfma_f32_16x16x32_f16(af0_1, bfr[0], acc1, 0, 0, 0);
    acc0 = __builtin_amdgcn_mfma_f32_16x16x32_f16(af1_0, bfr[1], acc0, 0, 0, 0);
    acc1 = __builtin_amdgcn_mfma_f32_16x16x32_f16(af1_1, bfr[1], acc1, 0, 0, 0);
    acc0 = __builtin_amdgcn_mfma_f32_16x16x32_f16(af2_0, bfr[2], acc0, 0, 0, 0);
    acc1 = __builtin_amdgcn_mfma_f32_16x16x32_f16(af2_1, bfr[2], acc1, 0, 0, 0);
    acc0 = __builtin_amdgcn_mfma_f32_16x16x32_f16(af3_0, bfr[3], acc0, 0, 0, 0);
    acc1 = __builtin_amdgcn_mfma_f32_16x16x32_f16(af3_1, bfr[3], acc1, 0, 0, 0);
    acc0 = __builtin_amdgcn_mfma_f32_16x16x32_f16(af4_0, bfr[4], acc0, 0, 0, 0);
    acc1 = __builtin_amdgcn_mfma_f32_16x16x32_f16(af4_1, bfr[4], acc1, 0, 0, 0);
    acc0 = __builtin_amdgcn_mfma_f32_16x16x32_f16(af5_0, bfr[5], acc0, 0, 0, 0);
    acc1 = __builtin_amdgcn_mfma_f32_16x16x32_f16(af5_1, bfr[5], acc1, 0, 0, 0);

    const float bb = b2[c];
    // C/D: col=lane&15 (=channel c), row=(lane>>4)*4+reg (=neighbor) -> max over rows
    float m0 = fmaxf(fmaxf(acc0[0], acc0[1]), fmaxf(acc0[2], acc0[3]));
    m0 = fmaxf(m0, __shfl_xor(m0, 16));
    m0 = fmaxf(m0, __shfl_xor(m0, 32));
    float m1 = fmaxf(fmaxf(acc1[0], acc1[1]), fmaxf(acc1[2], acc1[3]));
    m1 = fmaxf(m1, __shfl_xor(m1, 16));
    m1 = fmaxf(m1, __shfl_xor(m1, 32));
    if (lane < 16) {
      op0[c] = m0 + bb;
      op1[c] = m1 + bb;
    }
  }
}

extern "C" void kernel_launch(void* const* d_in, const int* in_sizes, int n_in,
                              void* d_out, int out_size, void* d_ws, size_t ws_size,
                              hipStream_t stream) {
  const float* point = (const float*)d_in[0];
  const float* W1    = (const float*)d_in[1];
  const float* b1    = (const float*)d_in[2];
  const float* W2    = (const float*)d_in[3];
  const float* b2    = (const float*)d_in[4];

  int*      idx_ws = (int*)d_ws;
  _Float16* W2T    = (_Float16*)((char*)d_ws + (1 << 20));

  prep_w2<<<(HDIM * CDIM + 255) / 256, 256, 0, stream>>>(W2, W2T);
  knn_kernel<<<512, 512, 0, stream>>>(point, idx_ws);
  mlp_kernel<<<NBATCH * 512, 512, 0, stream>>>(point, idx_ws, W1, b1, W2T, b2, (float*)d_out);
}

// Round 8
// 197.267 us; speedup vs baseline: 1.3265x; 1.3265x over previous
//
#include <hip/hip_runtime.h>

#define NPTS 4096
#define NBATCH 4
#define HDIM 192
#define CDIM 384

typedef _Float16 f16x8 __attribute__((ext_vector_type(8)));
typedef float f32x4 __attribute__((ext_vector_type(4)));

// ---------------- K0: W2 [192][384] f32 -> W2T [384][192] f16 ----------------
__global__ __launch_bounds__(256) void prep_w2(const float* __restrict__ W2,
                                               _Float16* __restrict__ W2T) {
  int i = blockIdx.x * 256 + threadIdx.x;
  if (i < HDIM * CDIM) {
    int h = i / CDIM, c = i % CDIM;
    W2T[c * HDIM + h] = (_Float16)W2[i];
  }
}

// ---------------- K1: KNN, filter-then-prune + per-query SHARED threshold ----------------
// (unchanged from R6/R7)
#define SCAP 30
#define FINF 3.4e38f

// macro, not lambda: a [&] lambda address-takes dl/il -> scratch spill (R2 lesson)
#define PRUNE()                                                                      \
  do {                                                                               \
    int mc = cnt;                                                                    \
    _Pragma("unroll")                                                                \
    for (int s = 32; s; s >>= 1) { int o = __shfl_xor(mc, s); mc = mc > o ? mc : o; }\
    mc = __builtin_amdgcn_readfirstlane(mc);                                         \
    for (int e = 0; e < mc; ++e) {                                                   \
      const int j = sstk[sbase + e] & 4095;                                          \
      const float dx = qx - spx[j];                                                  \
      const float dy = qy - spy[j];                                                  \
      const float dz = qz - spz[j];                                                  \
      const float d = __fadd_rn(__fadd_rn(__fmul_rn(dx, dx), __fmul_rn(dy, dy)),     \
                                __fmul_rn(dz, dz));                                  \
      const float v = (e < cnt && d < dl[15]) ? d : FINF;                            \
      bool cc[16];                                                                   \
      _Pragma("unroll")                                                              \
      for (int i = 0; i < 16; ++i) cc[i] = v < dl[i];                                \
      _Pragma("unroll")                                                              \
      for (int i = 15; i >= 1; --i) {                                                \
        dl[i] = cc[i] ? (cc[i - 1] ? dl[i - 1] : v) : dl[i];                         \
        il[i] = cc[i] ? (cc[i - 1] ? il[i - 1] : j) : il[i];                         \
      }                                                                              \
      dl[0] = cc[0] ? v : dl[0];                                                     \
      il[0] = cc[0] ? j : il[0];                                                     \
    }                                                                                \
    cnt = 0;                                                                         \
    thr = dl[15];                                                                    \
    atomicMin(&sThrU[ql], __float_as_uint(dl[15]));                                  \
  } while (0)

__global__ __launch_bounds__(512) void knn_kernel(const float* __restrict__ pts,
                                                  int* __restrict__ idx_out) {
  __shared__ float smem[12352];
  __shared__ float sstk_f[7680];
  __shared__ unsigned sThrU[32];
  unsigned short* sstk = (unsigned short*)sstk_f;

  float* spx = smem;
  float* spy = smem + 4096;
  float* spz = smem + 8192;

  const int t  = threadIdx.x;
  const int b  = blockIdx.x >> 7;
  const int qb = (blockIdx.x & 127) << 5;
  const float* P = pts + (size_t)b * NPTS * 3;

  for (int i = t; i < NPTS; i += 512) {
    spx[i] = P[3 * i + 0];
    spy[i] = P[3 * i + 1];
    spz[i] = P[3 * i + 2];
  }
  if (t < 32) sThrU[t] = __float_as_uint(FINF);
  __syncthreads();

  const int ql    = t & 31;
  const int q     = qb + ql;
  const int cid   = (t >> 5) & 15;
  const int cbase = cid << 8;
  const float qx = spx[q], qy = spy[q], qz = spz[q];

  float dl[16];
  int   il[16];
#pragma unroll
  for (int i = 0; i < 16; ++i) { dl[i] = FINF; il[i] = 0; }
  float thr = FINF;
  int   cnt = 0;
  const int sbase = t * SCAP;

  for (int jt = 0; jt < 256; jt += 8) {
    {  // refresh admission threshold (volatile: must observe other waves' atomicMin)
      const unsigned tb = ((volatile unsigned*)sThrU)[ql];
      thr = fminf(dl[15], __uint_as_float(tb));
    }
    const int jb = cbase + jt;
    const f32x4 x0 = *(const f32x4*)(spx + jb);
    const f32x4 x1 = *(const f32x4*)(spx + jb + 4);
    const f32x4 y0 = *(const f32x4*)(spy + jb);
    const f32x4 y1 = *(const f32x4*)(spy + jb + 4);
    const f32x4 z0 = *(const f32x4*)(spz + jb);
    const f32x4 z1 = *(const f32x4*)(spz + jb + 4);
#pragma unroll
    for (int u = 0; u < 8; ++u) {
      const float px = (u < 4) ? x0[u & 3] : x1[u & 3];
      const float py = (u < 4) ? y0[u & 3] : y1[u & 3];
      const float pz = (u < 4) ? z0[u & 3] : z1[u & 3];
      const float dx = qx - px;
      const float dy = qy - py;
      const float dz = qz - pz;
      // EXACT match to numpy/jax: ((dx*dx + dy*dy) + dz*dz), f32, no FMA contraction
      const float d = __fadd_rn(__fadd_rn(__fmul_rn(dx, dx), __fmul_rn(dy, dy)),
                                __fmul_rn(dz, dz));
      if (d <= thr) { sstk[sbase + cnt] = (unsigned short)(jb + u); ++cnt; }
    }
    if (__any(cnt >= SCAP - 8)) PRUNE();
  }
  PRUNE();

  __syncthreads();

  float*          md = smem;
  unsigned short* mi = (unsigned short*)(smem + 8224);
  const int lbase = ql * 257 + cid * 16;
#pragma unroll
  for (int i = 0; i < 16; ++i) {
    md[lbase + i] = dl[i];
    mi[lbase + i] = (unsigned short)il[i];
  }
  __syncthreads();

  float*          od = sstk_f;
  unsigned short* oi = (unsigned short*)(sstk_f + 2080);
  if (t < 128) {
    const int mq = t >> 2, g = t & 3;
    const int base = mq * 257 + g * 64;
    int p0 = 0, p1 = 0, p2 = 0, p3 = 0;
    const int ob = mq * 65 + g * 16;
    for (int r = 0; r < 16; ++r) {
      const float d0 = md[base + p0];
      const float d1 = md[base + 16 + p1];
      const float d2 = md[base + 32 + p2];
      const float d3 = md[base + 48 + p3];
      int bw = 0; float bd = d0;
      if (d1 < bd) { bd = d1; bw = 1; }
      if (d2 < bd) { bd = d2; bw = 2; }
      if (d3 < bd) { bd = d3; bw = 3; }
      const unsigned short bi = (bw == 0) ? mi[base + p0]
                              : (bw == 1) ? mi[base + 16 + p1]
                              : (bw == 2) ? mi[base + 32 + p2]
                                          : mi[base + 48 + p3];
      od[ob + r] = bd;
      oi[ob + r] = bi;
      p0 += (bw == 0); p1 += (bw == 1); p2 += (bw == 2); p3 += (bw == 3);
    }
  }
  __syncthreads();

  if (t < 32) {
    const int base = t * 65;
    int p0 = 0, p1 = 0, p2 = 0, p3 = 0;
    int* op = idx_out + (((size_t)b * NPTS + qb + t) << 4);
    for (int r = 0; r < 16; ++r) {
      const float d0 = od[base + p0];
      const float d1 = od[base + 16 + p1];
      const float d2 = od[base + 32 + p2];
      const float d3 = od[base + 48 + p3];
      int bw = 0; float bd = d0;
      if (d1 < bd) { bd = d1; bw = 1; }
      if (d2 < bd) { bd = d2; bw = 2; }
      if (d3 < bd) { bd = d3; bw = 3; }
      const unsigned short bi = (bw == 0) ? oi[base + p0]
                              : (bw == 1) ? oi[base + 16 + p1]
                              : (bw == 2) ? oi[base + 32 + p2]
                                          : oi[base + 48 + p3];
      op[r] = (int)bi;
      p0 += (bw == 0); p1 += (bw == 1); p2 += (bw == 2); p3 += (bw == 3);
    }
  }
}

// ---------------- K2: fused layer1(swish) -> f16 MFMA layer2 -> maxpool ----------------
// B-STATIONARY: wave wv owns ct-tiles 3wv..3wv+2. Its 18 B-frags (72 VGPR) load ONCE
// per block, pinned. qi-loop: 6 ds_read_b128 A-frags feed 18 MFMAs on 3 acc chains
// (unroll 2 -> 6 chains in flight). Zero global loads in steady state; A-read:MFMA=1:3.
// (R6/R7 failure: 2 chains/iter + 6 fresh L2 loads per 12 MFMAs -> MfmaUtil 8.5%.)
__global__ __launch_bounds__(512) void mlp_kernel(const float* __restrict__ pts,
                                                  const int* __restrict__ idx,
                                                  const float* __restrict__ W1,
                                                  const float* __restrict__ b1,
                                                  const _Float16* __restrict__ W2T,
                                                  const float* __restrict__ b2,
                                                  float* __restrict__ out) {
  __shared__ _Float16 sA[24576];   // 48 KB, fragment-major, chunk position == lane

  const int bid = blockIdx.x;
  const int b   = bid >> 9;
  const int qb  = (bid & 511) << 3;
  const float* P = pts + (size_t)b * NPTS * 3;
  const int t = threadIdx.x;
  const int lane = t & 63;

  // ---- stage A = f16(swish(f @ W1 + b1)) ----
  {
    const int r  = t & 15;           // neighbor slot
    const int kg = (t >> 4) & 3;     // k-slice (lane == kg*16 + r)
    const int qi = t >> 6;           // query within block
    const int qq = qb + qi;
    const int nb = idx[(((size_t)b * NPTS + qq) << 4) + r];
    const float pqx = P[qq * 3 + 0], pqy = P[qq * 3 + 1], pqz = P[qq * 3 + 2];
    float f[6];
    f[0] = P[nb * 3 + 0] - pqx;
    f[1] = P[nb * 3 + 1] - pqy;
    f[2] = P[nb * 3 + 2] - pqz;
    f[3] = pqx; f[4] = pqy; f[5] = pqz;
#pragma unroll
    for (int kt = 0; kt < 6; ++kt) {
      const int h0 = kt * 32 + kg * 8;
      f32x4 a0 = *(const f32x4*)(b1 + h0);
      f32x4 a1 = *(const f32x4*)(b1 + h0 + 4);
#pragma unroll
      for (int in = 0; in < 6; ++in) {
        const f32x4 w0 = *(const f32x4*)(W1 + in * HDIM + h0);
        const f32x4 w1 = *(const f32x4*)(W1 + in * HDIM + h0 + 4);
        a0 += f[in] * w0;
        a1 += f[in] * w1;
      }
      f16x8 v;
#pragma unroll
      for (int j = 0; j < 4; ++j) {
        const float s0 = a0[j] * __builtin_amdgcn_rcpf(1.0f + __expf(-a0[j]));
        const float s1 = a1[j] * __builtin_amdgcn_rcpf(1.0f + __expf(-a1[j]));
        v[j]     = (_Float16)s0;
        v[j + 4] = (_Float16)s1;
      }
      *(f16x8*)(sA + (((kt * 8 + qi) * 64) + lane) * 8) = v;   // base + lane*16 B
    }
  }
  __syncthreads();

  // ---- MFMA phase: wave wv owns ct = 3wv+{0,1,2}; B pinned in regs ----
  const int wv   = t >> 6;
  const int ln15 = lane & 15;
  const int kofs = (lane >> 4) * 8;
  const int c0 = (wv * 3 + 0) * 16 + ln15;
  const int c1 = (wv * 3 + 1) * 16 + ln15;
  const int c2 = (wv * 3 + 2) * 16 + ln15;

  f16x8 B0_0, B0_1, B0_2, B0_3, B0_4, B0_5;
  f16x8 B1_0, B1_1, B1_2, B1_3, B1_4, B1_5;
  f16x8 B2_0, B2_1, B2_2, B2_3, B2_4, B2_5;
#define LOAD_B(ci, kt, dst)                                                        \
  dst = *(const f16x8*)(W2T + (size_t)(ci) * HDIM + (kt) * 32 + kofs);             \
  asm volatile("" : "+v"(dst));   /* pin: keep resident across qi loop */
  LOAD_B(c0, 0, B0_0) LOAD_B(c0, 1, B0_1) LOAD_B(c0, 2, B0_2)
  LOAD_B(c0, 3, B0_3) LOAD_B(c0, 4, B0_4) LOAD_B(c0, 5, B0_5)
  LOAD_B(c1, 0, B1_0) LOAD_B(c1, 1, B1_1) LOAD_B(c1, 2, B1_2)
  LOAD_B(c1, 3, B1_3) LOAD_B(c1, 4, B1_4) LOAD_B(c1, 5, B1_5)
  LOAD_B(c2, 0, B2_0) LOAD_B(c2, 1, B2_1) LOAD_B(c2, 2, B2_2)
  LOAD_B(c2, 3, B2_3) LOAD_B(c2, 4, B2_4) LOAD_B(c2, 5, B2_5)
#undef LOAD_B

  const float bb0 = b2[c0];
  const float bb1 = b2[c1];
  const float bb2 = b2[c2];
  const size_t orow = (size_t)b * NPTS + qb;

#pragma unroll 2
  for (int qi = 0; qi < 8; ++qi) {
    f16x8 a0 = *(const f16x8*)(sA + (((0 * 8 + qi) * 64) + lane) * 8);
    f16x8 a1 = *(const f16x8*)(sA + (((1 * 8 + qi) * 64) + lane) * 8);
    f16x8 a2 = *(const f16x8*)(sA + (((2 * 8 + qi) * 64) + lane) * 8);
    f16x8 a3 = *(const f16x8*)(sA + (((3 * 8 + qi) * 64) + lane) * 8);
    f16x8 a4 = *(const f16x8*)(sA + (((4 * 8 + qi) * 64) + lane) * 8);
    f16x8 a5 = *(const f16x8*)(sA + (((5 * 8 + qi) * 64) + lane) * 8);

    f32x4 acc0 = {0.f, 0.f, 0.f, 0.f};
    f32x4 acc1 = {0.f, 0.f, 0.f, 0.f};
    f32x4 acc2 = {0.f, 0.f, 0.f, 0.f};
    acc0 = __builtin_amdgcn_mfma_f32_16x16x32_f16(a0, B0_0, acc0, 0, 0, 0);
    acc1 = __builtin_amdgcn_mfma_f32_16x16x32_f16(a0, B1_0, acc1, 0, 0, 0);
    acc2 = __builtin_amdgcn_mfma_f32_16x16x32_f16(a0, B2_0, acc2, 0, 0, 0);
    acc0 = __builtin_amdgcn_mfma_f32_16x16x32_f16(a1, B0_1, acc0, 0, 0, 0);
    acc1 = __builtin_amdgcn_mfma_f32_16x16x32_f16(a1, B1_1, acc1, 0, 0, 0);
    acc2 = __builtin_amdgcn_mfma_f32_16x16x32_f16(a1, B2_1, acc2, 0, 0, 0);
    acc0 = __builtin_amdgcn_mfma_f32_16x16x32_f16(a2, B0_2, acc0, 0, 0, 0);
    acc1 = __builtin_amdgcn_mfma_f32_16x16x32_f16(a2, B1_2, acc1, 0, 0, 0);
    acc2 = __builtin_amdgcn_mfma_f32_16x16x32_f16(a2, B2_2, acc2, 0, 0, 0);
    acc0 = __builtin_amdgcn_mfma_f32_16x16x32_f16(a3, B0_3, acc0, 0, 0, 0);
    acc1 = __builtin_amdgcn_mfma_f32_16x16x32_f16(a3, B1_3, acc1, 0, 0, 0);
    acc2 = __builtin_amdgcn_mfma_f32_16x16x32_f16(a3, B2_3, acc2, 0, 0, 0);
    acc0 = __builtin_amdgcn_mfma_f32_16x16x32_f16(a4, B0_4, acc0, 0, 0, 0);
    acc1 = __builtin_amdgcn_mfma_f32_16x16x32_f16(a4, B1_4, acc1, 0, 0, 0);
    acc2 = __builtin_amdgcn_mfma_f32_16x16x32_f16(a4, B2_4, acc2, 0, 0, 0);
    acc0 = __builtin_amdgcn_mfma_f32_16x16x32_f16(a5, B0_5, acc0, 0, 0, 0);
    acc1 = __builtin_amdgcn_mfma_f32_16x16x32_f16(a5, B1_5, acc1, 0, 0, 0);
    acc2 = __builtin_amdgcn_mfma_f32_16x16x32_f16(a5, B2_5, acc2, 0, 0, 0);

    // C/D: col=lane&15 (=channel), row=(lane>>4)*4+reg (=neighbor) -> max over rows
    float m0 = fmaxf(fmaxf(acc0[0], acc0[1]), fmaxf(acc0[2], acc0[3]));
    m0 = fmaxf(m0, __shfl_xor(m0, 16));
    m0 = fmaxf(m0, __shfl_xor(m0, 32));
    float m1 = fmaxf(fmaxf(acc1[0], acc1[1]), fmaxf(acc1[2], acc1[3]));
    m1 = fmaxf(m1, __shfl_xor(m1, 16));
    m1 = fmaxf(m1, __shfl_xor(m1, 32));
    float m2 = fmaxf(fmaxf(acc2[0], acc2[1]), fmaxf(acc2[2], acc2[3]));
    m2 = fmaxf(m2, __shfl_xor(m2, 16));
    m2 = fmaxf(m2, __shfl_xor(m2, 32));
    if (lane < 16) {
      float* op = out + (orow + qi) * CDIM;
      op[c0] = m0 + bb0;
      op[c1] = m1 + bb1;
      op[c2] = m2 + bb2;
    }
  }
}

extern "C" void kernel_launch(void* const* d_in, const int* in_sizes, int n_in,
                              void* d_out, int out_size, void* d_ws, size_t ws_size,
                              hipStream_t stream) {
  const float* point = (const float*)d_in[0];
  const float* W1    = (const float*)d_in[1];
  const float* b1    = (const float*)d_in[2];
  const float* W2    = (const float*)d_in[3];
  const float* b2    = (const float*)d_in[4];

  int*      idx_ws = (int*)d_ws;
  _Float16* W2T    = (_Float16*)((char*)d_ws + (1 << 20));

  prep_w2<<<(HDIM * CDIM + 255) / 256, 256, 0, stream>>>(W2, W2T);
  knn_kernel<<<512, 512, 0, stream>>>(point, idx_ws);
  mlp_kernel<<<NBATCH * 512, 512, 0, stream>>>(point, idx_ws, W1, b1, W2T, b2, (float*)d_out);
}